// Round 11
// baseline (5795.734 us; speedup 1.0000x reference)
//
#include <hip/hip_runtime.h>
#include <hip/hip_bf16.h>

#define TT 3650
#define HH 256
#define LDS_PAD 10240

typedef _Float16 f16x8 __attribute__((ext_vector_type(8)));
typedef float f32x4 __attribute__((ext_vector_type(4)));

__device__ __forceinline__ float xexp2(float x) { return __builtin_amdgcn_exp2f(x); }
__device__ __forceinline__ float xrcp(float x) { return __builtin_amdgcn_rcpf(x); }
__device__ __forceinline__ float xexp(float x) { return xexp2(x * 1.4426950408889634f); }
__device__ __forceinline__ float xtanh(float x) {
  float e = xexp2(x * 2.8853900817779268f);  // e^{2x}
  return 1.0f - 2.0f * xrcp(e + 1.0f);
}
__device__ __forceinline__ float xstep(float x) {  // sigmoid(10x)
  return xrcp(1.0f + xexp2(-14.426950408889634f * x));
}
__device__ __forceinline__ float xsinh(float x) {
  float e = xexp(x);
  return 0.5f * (e - xrcp(e));
}

// lane gets its value + the row_ror:N-permuted value (row = 16 lanes)
#define DPPADD(x, ctrl)                                                        \
  (x) += __builtin_bit_cast(float, __builtin_amdgcn_update_dpp(                \
            0, __builtin_bit_cast(int, (x)), (ctrl), 0xf, 0xf, false));

#define REP8(M) M(0) M(1) M(2) M(3) M(4) M(5) M(6) M(7)

// Weights stored as fp16 of (W * 2^10): no fp16-denormal weights (MFMA
// flushes denormal inputs; round-9 drift). Descale after the MFMA.
#define WSCALE 1024.0f
#define WDESCALE 0.0009765625f

__global__ void __launch_bounds__(512) exphydro_scan(
    const float* __restrict__ gin, const float* __restrict__ gdayl,
    const float* __restrict__ gW0, const float* __restrict__ gb0,
    const float* __restrict__ gW1, const float* __restrict__ gb1,
    const float* __restrict__ gW2, const float* __restrict__ gb2,
    const float* __restrict__ gWout, const float* __restrict__ gbout,
    float* __restrict__ gout) {
  __shared__ alignas(16) _Float16 h0l[HH];   // 512 B activation buffers
  __shared__ alignas(16) _Float16 h1l[HH];
  __shared__ float sWP[64];                  // [wave][slot]: w*8+m, m=0..4 used
  __shared__ float sP[TT], sTm[TT];
  __shared__ float sLd[TT + LDS_PAD];        // pad keeps 1 block/CU assumption

  const int tid = threadIdx.x;
  const int lane = tid & 63;
  const int w = tid >> 6;          // wave 0..7
  const int li = lane & 15;        // MFMA col within tile
  const int g = lane >> 4;         // k-group 0..3
  const int jA = 32 * w + 2 * li;  // paired j's -> one b32 h-write
  const int jB = jA + 1;

  // ---- stage forcings ----
  for (int i = tid; i < TT; i += 512) {
    sP[i] = gin[5 * i + 2];
    sTm[i] = gin[5 * i + 3];
    sLd[i] = gdayl[i];
  }
  if (tid < 64) sWP[tid] = 0.0f;   // slots m=5..7 stay 0 forever

  // ---- per-thread constants ----
  float s0 = gin[0], s1 = gin[1];
  const float bo0 = gbout[0], bo1 = gbout[1], bo2 = gbout[2], bo3 = gbout[3],
              bo4 = gbout[4];
  const float w0A0 = gW0[jA], w0A1 = gW0[HH + jA], w0A2 = gW0[2 * HH + jA],
              w0A3 = gW0[3 * HH + jA];
  const float w0B0 = gW0[jB], w0B1 = gW0[HH + jB], w0B2 = gW0[2 * HH + jB],
              w0B3 = gW0[3 * HH + jB];
  const float b0A = gb0[jA], b0B = gb0[jB], b1A = gb1[jA], b1B = gb1[jB],
              b2A = gb2[jA], b2B = gb2[jB];
  const float woA0 = gWout[5 * jA + 0], woA1 = gWout[5 * jA + 1],
              woA2 = gWout[5 * jA + 2], woA3 = gWout[5 * jA + 3],
              woA4 = gWout[5 * jA + 4];
  const float woB0 = gWout[5 * jB + 0], woB1 = gWout[5 * jB + 1],
              woB2 = gWout[5 * jB + 2], woB3 = gWout[5 * jB + 3],
              woB4 = gWout[5 * jB + 4];

  // ---- weight B-fragments -> AGPRs (native MFMA operands).
  // Fragment for slice i: lane holds B[k][col=li] for k = 32i + 8g + e.
#define FDECL(i) f16x8 a1A_##i, a1B_##i, a2A_##i, a2B_##i;
  REP8(FDECL)
#undef FDECL
#define MK(dst, G, i, j)                                                       \
  {                                                                            \
    const float* p = (G) + (32 * (i) + g * 8) * HH + (j);                      \
    f16x8 f;                                                                   \
    f[0] = (_Float16)(p[0] * WSCALE);      f[1] = (_Float16)(p[HH] * WSCALE);  \
    f[2] = (_Float16)(p[2 * HH] * WSCALE); f[3] = (_Float16)(p[3 * HH] * WSCALE); \
    f[4] = (_Float16)(p[4 * HH] * WSCALE); f[5] = (_Float16)(p[5 * HH] * WSCALE); \
    f[6] = (_Float16)(p[6 * HH] * WSCALE); f[7] = (_Float16)(p[7 * HH] * WSCALE); \
    dst = f;                                                                   \
    asm volatile("" : "+a"(dst));                                              \
  }
#define FINIT(i) MK(a1A_##i, gW1, i, jA) MK(a1B_##i, gW1, i, jB)               \
                 MK(a2A_##i, gW2, i, jA) MK(a2B_##i, gW2, i, jB)
  REP8(FINIT)
#undef FINIT
#undef MK

  const char* hp0 = (const char*)h0l + g * 16;  // A-fill base (k-group window)
  const char* hp1 = (const char*)h1l + g * 16;

#define MFMA(acc, a, b)                                                        \
  asm("v_mfma_f32_16x16x32_f16 %0, %1, %2, %0" : "+v"(acc) : "v"(a), "a"(b));

  __syncthreads();  // staging + sWP zero visible

  for (int t = 0; t < TT; ++t) {
    const float p_in = sP[t];
    const float tm = sTm[t];
    const float ld = sLd[t];

    // ---- layer 0 (VALU, per-lane j; groups 1-3 redundant) ----
    float h0A = xtanh(b0A + s0 * w0A0 + s1 * w0A1 + p_in * w0A2 + tm * w0A3);
    float h0B = xtanh(b0B + s0 * w0B0 + s1 * w0B1 + p_in * w0B2 + tm * w0B3);
    if (lane < 16) {
      unsigned hw =
          (unsigned)__builtin_bit_cast(unsigned short, (_Float16)h0A) |
          ((unsigned)__builtin_bit_cast(unsigned short, (_Float16)h0B) << 16);
      *(unsigned*)((char*)h0l + (jA << 1)) = hw;
    }
    __syncthreads();  // A

    // ---- layer 1: cluster the 8 LDS reads, then 16 MFMA on 4 independent
    // 4-deep chains (dA0/dB0 slices 0-3, dA1/dB1 slices 4-7) ----
    {
      f16x8 av0 = *(const f16x8*)(hp0 + 0 * 64);
      f16x8 av1 = *(const f16x8*)(hp0 + 1 * 64);
      f16x8 av2 = *(const f16x8*)(hp0 + 2 * 64);
      f16x8 av3 = *(const f16x8*)(hp0 + 3 * 64);
      f16x8 av4 = *(const f16x8*)(hp0 + 4 * 64);
      f16x8 av5 = *(const f16x8*)(hp0 + 5 * 64);
      f16x8 av6 = *(const f16x8*)(hp0 + 6 * 64);
      f16x8 av7 = *(const f16x8*)(hp0 + 7 * 64);
      f32x4 dA0 = {0.f, 0.f, 0.f, 0.f}, dB0 = {0.f, 0.f, 0.f, 0.f};
      f32x4 dA1 = {0.f, 0.f, 0.f, 0.f}, dB1 = {0.f, 0.f, 0.f, 0.f};
      asm volatile("s_nop 1"
                   : "+v"(dA0), "+v"(dB0), "+v"(dA1), "+v"(dB1));
      MFMA(dA0, av0, a1A_0) MFMA(dB0, av0, a1B_0)
      MFMA(dA1, av4, a1A_4) MFMA(dB1, av4, a1B_4)
      MFMA(dA0, av1, a1A_1) MFMA(dB0, av1, a1B_1)
      MFMA(dA1, av5, a1A_5) MFMA(dB1, av5, a1B_5)
      MFMA(dA0, av2, a1A_2) MFMA(dB0, av2, a1B_2)
      MFMA(dA1, av6, a1A_6) MFMA(dB1, av6, a1B_6)
      MFMA(dA0, av3, a1A_3) MFMA(dB0, av3, a1B_3)
      MFMA(dA1, av7, a1A_7) MFMA(dB1, av7, a1B_7)
      asm volatile("s_nop 7\n\ts_nop 7"
                   : "+v"(dA0), "+v"(dB0), "+v"(dA1), "+v"(dB1));
      float h1A = xtanh((dA0[0] + dA1[0]) * WDESCALE + b1A);
      float h1B = xtanh((dB0[0] + dB1[0]) * WDESCALE + b1B);
      if (lane < 16) {
        unsigned hw =
            (unsigned)__builtin_bit_cast(unsigned short, (_Float16)h1A) |
            ((unsigned)__builtin_bit_cast(unsigned short, (_Float16)h1B) << 16);
        *(unsigned*)((char*)h1l + (jA << 1)) = hw;
      }
    }
    __syncthreads();  // B

    // ---- layer 2 (same schedule) ----
    float h2A, h2B;
    {
      f16x8 av0 = *(const f16x8*)(hp1 + 0 * 64);
      f16x8 av1 = *(const f16x8*)(hp1 + 1 * 64);
      f16x8 av2 = *(const f16x8*)(hp1 + 2 * 64);
      f16x8 av3 = *(const f16x8*)(hp1 + 3 * 64);
      f16x8 av4 = *(const f16x8*)(hp1 + 4 * 64);
      f16x8 av5 = *(const f16x8*)(hp1 + 5 * 64);
      f16x8 av6 = *(const f16x8*)(hp1 + 6 * 64);
      f16x8 av7 = *(const f16x8*)(hp1 + 7 * 64);
      f32x4 eA0 = {0.f, 0.f, 0.f, 0.f}, eB0 = {0.f, 0.f, 0.f, 0.f};
      f32x4 eA1 = {0.f, 0.f, 0.f, 0.f}, eB1 = {0.f, 0.f, 0.f, 0.f};
      asm volatile("s_nop 1"
                   : "+v"(eA0), "+v"(eB0), "+v"(eA1), "+v"(eB1));
      MFMA(eA0, av0, a2A_0) MFMA(eB0, av0, a2B_0)
      MFMA(eA1, av4, a2A_4) MFMA(eB1, av4, a2B_4)
      MFMA(eA0, av1, a2A_1) MFMA(eB0, av1, a2B_1)
      MFMA(eA1, av5, a2A_5) MFMA(eB1, av5, a2B_5)
      MFMA(eA0, av2, a2A_2) MFMA(eB0, av2, a2B_2)
      MFMA(eA1, av6, a2A_6) MFMA(eB1, av6, a2B_6)
      MFMA(eA0, av3, a2A_3) MFMA(eB0, av3, a2B_3)
      MFMA(eA1, av7, a2A_7) MFMA(eB1, av7, a2B_7)
      asm volatile("s_nop 7\n\ts_nop 7"
                   : "+v"(eA0), "+v"(eB0), "+v"(eA1), "+v"(eB1));
      h2A = xtanh((eA0[0] + eA1[0]) * WDESCALE + b2A);
      h2B = xtanh((eB0[0] + eB1[0]) * WDESCALE + b2B);
    }

    // ---- output layer: per-lane partials, DPP row all-reduce (no DS) ----
    float p0 = h2A * woA0 + h2B * woB0;
    float p1 = h2A * woA1 + h2B * woB1;
    float p2 = h2A * woA2 + h2B * woB2;
    float p3 = h2A * woA3 + h2B * woB3;
    float p4 = h2A * woA4 + h2B * woB4;
    DPPADD(p0, 0x121) DPPADD(p0, 0x122) DPPADD(p0, 0x124) DPPADD(p0, 0x128)
    DPPADD(p1, 0x121) DPPADD(p1, 0x122) DPPADD(p1, 0x124) DPPADD(p1, 0x128)
    DPPADD(p2, 0x121) DPPADD(p2, 0x122) DPPADD(p2, 0x124) DPPADD(p2, 0x128)
    DPPADD(p3, 0x121) DPPADD(p3, 0x122) DPPADD(p3, 0x124) DPPADD(p3, 0x128)
    DPPADD(p4, 0x121) DPPADD(p4, 0x122) DPPADD(p4, 0x124) DPPADD(p4, 0x128)
    if (lane == 0) {  // lane 0 holds the wave's 32-j sums after row reduce
      sWP[w * 8 + 0] = p0; sWP[w * 8 + 1] = p1; sWP[w * 8 + 2] = p2;
      sWP[w * 8 + 3] = p3; sWP[w * 8 + 4] = p4;
    }
    __syncthreads();  // C

    // ---- finalize on ALL threads: cross-wave sum + transforms + state ----
    float v = sWP[lane];  // lane l: m = l&7, wave = l>>3 (m>4 slots are 0)
    DPPADD(v, 0x128)      // + rotated-by-8 within row: wave pairs
    v += __builtin_bit_cast(
        float, __builtin_amdgcn_ds_swizzle(__builtin_bit_cast(int, v), 0x401F));  // ^16
    float o0 = __builtin_bit_cast(float, __builtin_amdgcn_readlane(__builtin_bit_cast(int, v), 0)) +
               __builtin_bit_cast(float, __builtin_amdgcn_readlane(__builtin_bit_cast(int, v), 32)) + bo0;
    float o1 = __builtin_bit_cast(float, __builtin_amdgcn_readlane(__builtin_bit_cast(int, v), 1)) +
               __builtin_bit_cast(float, __builtin_amdgcn_readlane(__builtin_bit_cast(int, v), 33)) + bo1;
    float o2 = __builtin_bit_cast(float, __builtin_amdgcn_readlane(__builtin_bit_cast(int, v), 2)) +
               __builtin_bit_cast(float, __builtin_amdgcn_readlane(__builtin_bit_cast(int, v), 34)) + bo2;
    float o3 = __builtin_bit_cast(float, __builtin_amdgcn_readlane(__builtin_bit_cast(int, v), 3)) +
               __builtin_bit_cast(float, __builtin_amdgcn_readlane(__builtin_bit_cast(int, v), 35)) + bo3;
    float o4 = __builtin_bit_cast(float, __builtin_amdgcn_readlane(__builtin_bit_cast(int, v), 4)) +
               __builtin_bit_cast(float, __builtin_amdgcn_readlane(__builtin_bit_cast(int, v), 36)) + bo4;
    if (tid == 0) {
      gout[t] = o4;           // q_output[t] = raw mlp output m=4 at state_t
      gout[TT + t] = s0;      // s_snow_nn[t] (pre-update)
      gout[2 * TT + t] = s1;  // s_water_nn[t]
    }
    float sh0 = xsinh(o0), sh1 = xsinh(o1), sh2 = xsinh(o2);
    float e3 = xexp(o3), e4 = xexp(o4);
    float stn = xstep(-tm), st0 = xstep(s0), st1 = xstep(s1);
    float psn = fmaxf(sh0 * stn, 0.0f);
    float prn = fmaxf(sh1, 0.0f);
    float mm = fmaxf(st0 * sh2, 0.0f);
    float evt = st1 * e3 * ld;
    float qq = st1 * e4;
    s0 += psn - mm;                 // DT = 1
    s1 += prn + mm - evt - qq;
  }
#undef MFMA
}

extern "C" void kernel_launch(void* const* d_in, const int* in_sizes, int n_in,
                              void* d_out, int out_size, void* d_ws, size_t ws_size,
                              hipStream_t stream) {
  const float* gin   = (const float*)d_in[0];
  const float* gdayl = (const float*)d_in[1];
  const float* gW0   = (const float*)d_in[2];
  const float* gb0   = (const float*)d_in[3];
  const float* gW1   = (const float*)d_in[4];
  const float* gb1   = (const float*)d_in[5];
  const float* gW2   = (const float*)d_in[6];
  const float* gb2   = (const float*)d_in[7];
  const float* gWout = (const float*)d_in[8];
  const float* gbout = (const float*)d_in[9];
  float* gout = (float*)d_out;
  exphydro_scan<<<dim3(1), dim3(512), 0, stream>>>(
      gin, gdayl, gW0, gb0, gW1, gb1, gW2, gb2, gWout, gbout, gout);
}

// Round 12
// 4955.777 us; speedup vs baseline: 1.1695x; 1.1695x over previous
//
#include <hip/hip_runtime.h>
#include <hip/hip_bf16.h>

#define TT 3650
#define HH 256

typedef _Float16 f16x4 __attribute__((ext_vector_type(4)));
typedef _Float16 f16x8 __attribute__((ext_vector_type(8)));
typedef float f32x4 __attribute__((ext_vector_type(4)));

__device__ __forceinline__ float xexp2(float x) { return __builtin_amdgcn_exp2f(x); }
__device__ __forceinline__ float xrcp(float x) { return __builtin_amdgcn_rcpf(x); }
__device__ __forceinline__ float xexp(float x) { return xexp2(x * 1.4426950408889634f); }
__device__ __forceinline__ float xtanh(float x) {
  float e = xexp2(x * 2.8853900817779268f);  // e^{2x}
  return 1.0f - 2.0f * xrcp(e + 1.0f);
}
__device__ __forceinline__ float xstep(float x) {  // sigmoid(10x)
  return xrcp(1.0f + xexp2(-14.426950408889634f * x));
}
__device__ __forceinline__ float xsinh(float x) {
  float e = xexp(x);
  return 0.5f * (e - xrcp(e));
}

#define DPPADD(x, ctrl)                                                        \
  (x) += __builtin_bit_cast(float, __builtin_amdgcn_update_dpp(                \
            0, __builtin_bit_cast(int, (x)), (ctrl), 0xf, 0xf, false));
#define RDLANE(x, l)                                                           \
  __builtin_bit_cast(float,                                                    \
      __builtin_amdgcn_readlane(__builtin_bit_cast(int, (x)), (l)))

#define REP8(M) M(0) M(1) M(2) M(3) M(4) M(5) M(6) M(7)
#define REPC(M) M(0) M(1) M(2) M(3)

// Weights stored as fp16 of (W * 2^10): avoids fp16-denormal weights, which
// the MFMA pipe flushes (round-9 drift). Descale folded into the post-MFMA FMA.
#define WSCALE 1024.0f
#define WDESCALE 0.0009765625f

// 4 waves / 256 threads: halves the per-CU LDS instruction stream (the pipe
// that round-10 analysis says is binding) while keeping the same 256 MFMA/step.
// 64 weight fragments/wave = 256 AGPRs, legal only at 1 wave/EU -> declared
// via __launch_bounds__(256, 1); the ~84 KB LDS also forces 1 block/CU.
#define SF_PAD 1500

__global__ void __launch_bounds__(256, 1) exphydro_scan(
    const float* __restrict__ gin, const float* __restrict__ gdayl,
    const float* __restrict__ gW0, const float* __restrict__ gb0,
    const float* __restrict__ gW1, const float* __restrict__ gb1,
    const float* __restrict__ gW2, const float* __restrict__ gb2,
    const float* __restrict__ gWout, const float* __restrict__ gbout,
    float* __restrict__ gout) {
  __shared__ alignas(16) _Float16 h0l[HH];   // 512 B activation buffers
  __shared__ alignas(16) _Float16 h1l[HH];
  __shared__ float sWP[64];                  // [m][w]: slot m*4+w, 20 used
  __shared__ f32x4 sF[TT + SF_PAD];          // packed forcings {p,tm,ld,0} + pad

  const int tid = threadIdx.x;
  const int lane = tid & 63;
  const int w = tid >> 6;          // wave 0..3
  const int li = lane & 15;        // MFMA col within tile
  const int g = lane >> 4;         // k-group 0..3
  const int jb = 64 * w + 4 * li;  // this lane's 4 consecutive j's: jb+0..3

  // ---- stage packed forcings ----
  for (int i = tid; i < TT; i += 256) {
    f32x4 F = {gin[5 * i + 2], gin[5 * i + 3], gdayl[i], 0.0f};
    sF[i] = F;
  }
  if (tid < 64) sWP[tid] = 0.0f;   // slots >=20 stay 0 forever

  // ---- per-thread constants (j = jb + c, c = 0..3) ----
  float s0 = gin[0], s1 = gin[1];
  const float bo0 = gbout[0], bo1 = gbout[1], bo2 = gbout[2], bo3 = gbout[3],
              bo4 = gbout[4];
#define CDECL(c)                                                               \
  const float w00_##c = gW0[jb + (c)], w01_##c = gW0[HH + jb + (c)],           \
              w02_##c = gW0[2 * HH + jb + (c)],                                \
              w03_##c = gW0[3 * HH + jb + (c)], b0_##c = gb0[jb + (c)],        \
              b1_##c = gb1[jb + (c)], b2_##c = gb2[jb + (c)],                  \
              wo0_##c = gWout[5 * (jb + (c)) + 0],                             \
              wo1_##c = gWout[5 * (jb + (c)) + 1],                             \
              wo2_##c = gWout[5 * (jb + (c)) + 2],                             \
              wo3_##c = gWout[5 * (jb + (c)) + 3],                             \
              wo4_##c = gWout[5 * (jb + (c)) + 4];
  REPC(CDECL)
#undef CDECL

  // ---- weight B-fragments -> AGPRs (native MFMA operands, r10-proven).
  // Fragment (layer L, chain c, slice i): lane holds B[k][col=li] with
  // k = 32i + 8g + e, column j = jb + c.
#define FDECL(i) f16x8 a1_0_##i, a1_1_##i, a1_2_##i, a1_3_##i,                 \
                       a2_0_##i, a2_1_##i, a2_2_##i, a2_3_##i;
  REP8(FDECL)
#undef FDECL
#define MK(dst, G, i, c)                                                       \
  {                                                                            \
    const float* p = (G) + (32 * (i) + g * 8) * HH + jb + (c);                 \
    f16x8 f;                                                                   \
    f[0] = (_Float16)(p[0] * WSCALE);      f[1] = (_Float16)(p[HH] * WSCALE);  \
    f[2] = (_Float16)(p[2 * HH] * WSCALE); f[3] = (_Float16)(p[3 * HH] * WSCALE); \
    f[4] = (_Float16)(p[4 * HH] * WSCALE); f[5] = (_Float16)(p[5 * HH] * WSCALE); \
    f[6] = (_Float16)(p[6 * HH] * WSCALE); f[7] = (_Float16)(p[7 * HH] * WSCALE); \
    dst = f;                                                                   \
    asm volatile("" : "+a"(dst));                                              \
  }
#define FINIT(i)                                                               \
  MK(a1_0_##i, gW1, i, 0) MK(a1_1_##i, gW1, i, 1)                              \
  MK(a1_2_##i, gW1, i, 2) MK(a1_3_##i, gW1, i, 3)                              \
  MK(a2_0_##i, gW2, i, 0) MK(a2_1_##i, gW2, i, 1)                              \
  MK(a2_2_##i, gW2, i, 2) MK(a2_3_##i, gW2, i, 3)
  REP8(FINIT)
#undef FINIT
#undef MK

  const char* hp0 = (const char*)h0l + g * 16;  // A-fill base (k-group window)
  const char* hp1 = (const char*)h1l + g * 16;

#define MFMA(acc, a, b)                                                        \
  asm("v_mfma_f32_16x16x32_f16 %0, %1, %2, %0" : "+v"(acc) : "v"(a), "a"(b));

  __syncthreads();  // staging + sWP zero visible

  for (int t = 0; t < TT; ++t) {
    f32x4 F = sF[t];
    const float p_in = F[0];
    const float tm = F[1];
    const float ld = F[2];

    // ---- layer 0 (VALU; each lane computes its 4 j's, g>0 redundant) ----
#define L0C(c)                                                                 \
  float h0_##c =                                                               \
      xtanh(b0_##c + s0 * w00_##c + s1 * w01_##c + p_in * w02_##c + tm * w03_##c);
    REPC(L0C)
#undef L0C
    if (lane < 16) {
      f16x4 hv = {(_Float16)h0_0, (_Float16)h0_1, (_Float16)h0_2,
                  (_Float16)h0_3};
      *(f16x4*)((char*)h0l + (jb << 1)) = hv;  // one ds_write_b64
    }
    __syncthreads();  // A

    // ---- layer 1: 32 MFMA on 4 independent chains (one per j-subcolumn c);
    // the same av feeds all 4 chains, so DS reads stay at 8/wave ----
    f32x4 d0 = {0.f, 0.f, 0.f, 0.f}, d1 = {0.f, 0.f, 0.f, 0.f};
    f32x4 d2 = {0.f, 0.f, 0.f, 0.f}, d3 = {0.f, 0.f, 0.f, 0.f};
    asm volatile("s_nop 1" : "+v"(d0), "+v"(d1), "+v"(d2), "+v"(d3));
#define MM1(i)                                                                 \
  {                                                                            \
    f16x8 av = *(const f16x8*)(hp0 + (i) * 64);                                \
    MFMA(d0, av, a1_0_##i) MFMA(d1, av, a1_1_##i)                              \
    MFMA(d2, av, a1_2_##i) MFMA(d3, av, a1_3_##i)                              \
  }
    REP8(MM1)
#undef MM1
    asm volatile("s_nop 7\n\ts_nop 7" : "+v"(d0), "+v"(d1), "+v"(d2), "+v"(d3));
#define H1C(c) float h1_##c = xtanh(d##c[0] * WDESCALE + b1_##c);
    REPC(H1C)
#undef H1C
    if (lane < 16) {
      f16x4 hv = {(_Float16)h1_0, (_Float16)h1_1, (_Float16)h1_2,
                  (_Float16)h1_3};
      *(f16x4*)((char*)h1l + (jb << 1)) = hv;
    }
    __syncthreads();  // B

    // ---- layer 2 (same schedule) ----
    f32x4 e0 = {0.f, 0.f, 0.f, 0.f}, e1 = {0.f, 0.f, 0.f, 0.f};
    f32x4 e2 = {0.f, 0.f, 0.f, 0.f}, e3 = {0.f, 0.f, 0.f, 0.f};
    asm volatile("s_nop 1" : "+v"(e0), "+v"(e1), "+v"(e2), "+v"(e3));
#define MM2(i)                                                                 \
  {                                                                            \
    f16x8 av = *(const f16x8*)(hp1 + (i) * 64);                                \
    MFMA(e0, av, a2_0_##i) MFMA(e1, av, a2_1_##i)                              \
    MFMA(e2, av, a2_2_##i) MFMA(e3, av, a2_3_##i)                              \
  }
    REP8(MM2)
#undef MM2
    asm volatile("s_nop 7\n\ts_nop 7" : "+v"(e0), "+v"(e1), "+v"(e2), "+v"(e3));
#define H2C(c) float h2_##c = xtanh(e##c[0] * WDESCALE + b2_##c);
    REPC(H2C)
#undef H2C

    // ---- output layer: per-lane partials over 4 j's, DPP row all-reduce ----
    float p0 = h2_0 * wo0_0 + h2_1 * wo0_1 + h2_2 * wo0_2 + h2_3 * wo0_3;
    float p1 = h2_0 * wo1_0 + h2_1 * wo1_1 + h2_2 * wo1_2 + h2_3 * wo1_3;
    float p2 = h2_0 * wo2_0 + h2_1 * wo2_1 + h2_2 * wo2_2 + h2_3 * wo2_3;
    float p3 = h2_0 * wo3_0 + h2_1 * wo3_1 + h2_2 * wo3_2 + h2_3 * wo3_3;
    float p4 = h2_0 * wo4_0 + h2_1 * wo4_1 + h2_2 * wo4_2 + h2_3 * wo4_3;
    DPPADD(p0, 0x121) DPPADD(p0, 0x122) DPPADD(p0, 0x124) DPPADD(p0, 0x128)
    DPPADD(p1, 0x121) DPPADD(p1, 0x122) DPPADD(p1, 0x124) DPPADD(p1, 0x128)
    DPPADD(p2, 0x121) DPPADD(p2, 0x122) DPPADD(p2, 0x124) DPPADD(p2, 0x128)
    DPPADD(p3, 0x121) DPPADD(p3, 0x122) DPPADD(p3, 0x124) DPPADD(p3, 0x128)
    DPPADD(p4, 0x121) DPPADD(p4, 0x122) DPPADD(p4, 0x124) DPPADD(p4, 0x128)
    // every lane now holds the wave's 64-j sums; lane m (<5) writes slot m*4+w
    float pv = lane == 0 ? p0 : lane == 1 ? p1 : lane == 2 ? p2
                                          : lane == 3 ? p3 : p4;
    if (lane < 5) sWP[lane * 4 + w] = pv;
    __syncthreads();  // C

    // ---- finalize on ALL threads: quad-xor reduce over w, transforms ----
    float v = sWP[lane];  // lane l: m = l>>2, w = l&3 (slots >=20 are 0)
    DPPADD(v, 0xB1)       // quad_perm xor1
    DPPADD(v, 0x4E)       // quad_perm xor2 -> all 4 lanes of quad m hold o_m
    float o0 = RDLANE(v, 0) + bo0;
    float o1 = RDLANE(v, 4) + bo1;
    float o2 = RDLANE(v, 8) + bo2;
    float o3 = RDLANE(v, 12) + bo3;
    float o4 = RDLANE(v, 16) + bo4;
    if (tid == 0) {
      gout[t] = o4;           // q_output[t] = raw mlp output m=4 at state_t
      gout[TT + t] = s0;      // s_snow_nn[t] (pre-update)
      gout[2 * TT + t] = s1;  // s_water_nn[t]
    }
    float sh0 = xsinh(o0), sh1 = xsinh(o1), sh2 = xsinh(o2);
    float e3x = xexp(o3), e4x = xexp(o4);
    float stn = xstep(-tm), st0 = xstep(s0), st1 = xstep(s1);
    float psn = fmaxf(sh0 * stn, 0.0f);
    float prn = fmaxf(sh1, 0.0f);
    float mm = fmaxf(st0 * sh2, 0.0f);
    float evt = st1 * e3x * ld;
    float qq = st1 * e4x;
    s0 += psn - mm;                 // DT = 1
    s1 += prn + mm - evt - qq;
  }
#undef MFMA
}

extern "C" void kernel_launch(void* const* d_in, const int* in_sizes, int n_in,
                              void* d_out, int out_size, void* d_ws, size_t ws_size,
                              hipStream_t stream) {
  const float* gin   = (const float*)d_in[0];
  const float* gdayl = (const float*)d_in[1];
  const float* gW0   = (const float*)d_in[2];
  const float* gb0   = (const float*)d_in[3];
  const float* gW1   = (const float*)d_in[4];
  const float* gb1   = (const float*)d_in[5];
  const float* gW2   = (const float*)d_in[6];
  const float* gb2   = (const float*)d_in[7];
  const float* gWout = (const float*)d_in[8];
  const float* gbout = (const float*)d_in[9];
  float* gout = (float*)d_out;
  exphydro_scan<<<dim3(1), dim3(256), 0, stream>>>(
      gin, gdayl, gW0, gb0, gW1, gb1, gW2, gb2, gWout, gbout, gout);
}